// Round 1
// baseline (237.114 us; speedup 1.0000x reference)
//
#include <hip/hip_runtime.h>
#include <hip/hip_bf16.h>

// SoftMoEGating: B=8, S=4096, D=1024, E=8, P=4, K=E*P=32
#define B 8
#define S 4096
#define DD 1024
#define KK 32

typedef __attribute__((ext_vector_type(8))) short bf16x8;
typedef __attribute__((ext_vector_type(16))) float f32x16;

static __device__ __forceinline__ unsigned short f2bf(float f) {
    unsigned int u = __builtin_bit_cast(unsigned int, f);
    u += 0x7FFFu + ((u >> 16) & 1u);     // RNE
    return (unsigned short)(u >> 16);
}

static __device__ __forceinline__ unsigned int pack2bf(float lo, float hi) {
    return (unsigned int)f2bf(lo) | ((unsigned int)f2bf(hi) << 16);
}

static __device__ __forceinline__ void gload_lds16(const void* g, void* l) {
    __builtin_amdgcn_global_load_lds(
        (const __attribute__((address_space(1))) unsigned int*)g,
        (__attribute__((address_space(3))) unsigned int*)l, 16, 0, 0);
}

// ---------------------------------------------------------------------------
// K0: phi [1024 d][32 k] fp32  ->  phiT [32 k][1024 d] bf16 (B-operand layout).
// (unchanged)
// ---------------------------------------------------------------------------
__global__ __launch_bounds__(256) void k0_phit(const float* __restrict__ phi,
                                               unsigned short* __restrict__ phiT) {
    __shared__ float lt[32][33];
    const int d0 = blockIdx.x * 32;
    const int tid = threadIdx.x;
#pragma unroll
    for (int i = 0; i < 4; ++i) {
        int slot = tid + i * 256;
        int d = slot >> 5, k = slot & 31;
        lt[d][k] = phi[(size_t)(d0 + d) * KK + k];
    }
    __syncthreads();
    const int k = tid >> 3, c = tid & 7, d = c * 4;
    short4 pk;
    pk.x = (short)f2bf(lt[d + 0][k]);
    pk.y = (short)f2bf(lt[d + 1][k]);
    pk.z = (short)f2bf(lt[d + 2][k]);
    pk.w = (short)f2bf(lt[d + 3][k]);
    *(short4*)(phiT + (size_t)k * DD + d0 + d) = pk;
}

// ---------------------------------------------------------------------------
// K1: logits via MFMA 32x32x16 bf16. grid = 8b x 32 stile(128 s) x 2 dq = 512.
// NEW: no x-LDS staging (zero intra-block reuse of x) — A-fragments loaded
// directly from global (8 contiguous fp32/lane = 2 x dwordx4; lanes l,l+32
// cover 64 contiguous bytes of the same token row). phiT half [32k][512d]
// bf16 LDS-resident, 16B-block XOR-swizzled for conflict-free b128 B-frags.
// Barriers: 2 total (after phiT stage, before epilogue transpose) vs 16.
// ---------------------------------------------------------------------------
__global__ __launch_bounds__(256) void k1_logits(const float* __restrict__ x,
                                                 const unsigned short* __restrict__ phiT,
                                                 const float* __restrict__ bias,
                                                 float* __restrict__ lp) {
    __shared__ __align__(16) char sm[32768];
    __shared__ float lt[32][129];

    const int bid = blockIdx.x;
    const int dq = bid & 1;
    const int st = (bid >> 1) & 31;
    const int b  = bid >> 6;
    const int tid = threadIdx.x;
    const int wv = __builtin_amdgcn_readfirstlane(tid >> 6);
    const int lane = tid & 63;
    const int l31 = lane & 31;
    const int half = lane >> 5;

    // stage phiT half-slice [32 k][512 d] bf16 (32 KB), 16B-block XOR-swizzle
    {
        const uint4* pg = (const uint4*)phiT;   // full row = 128 uint4
#pragma unroll
        for (int i = 0; i < 8; ++i) {
            int slot = tid + i * 256;
            int k = slot >> 6, blk = slot & 63;
            uint4 v = pg[(size_t)k * 128 + dq * 64 + blk];
            *(uint4*)(sm + (size_t)k * 1024 + ((blk ^ (k & 7)) << 4)) = v;
        }
    }

    f32x16 acc;
    {
        float bv = (dq == 0) ? bias[l31] : 0.f;
#pragma unroll
        for (int r = 0; r < 16; ++r) acc[r] = bv;
    }
    __syncthreads();

    // A: row s = st*128 + wv*32 + l31; k-cols of MFMA = half*8 + j  (d-dim)
    const float* xg = x + ((size_t)(b * S + st * 128 + wv * 32 + l31)) * DD
                        + dq * 512 + half * 8;
    const int kx = l31 & 7;
    const char* brow = sm + (size_t)l31 * 1024;

#pragma unroll 8
    for (int ch = 0; ch < 32; ++ch) {
        float4 a0 = *(const float4*)(xg + ch * 16);
        float4 a1 = *(const float4*)(xg + ch * 16 + 4);
        unsigned int p0 = pack2bf(a0.x, a0.y);
        unsigned int p1 = pack2bf(a0.z, a0.w);
        unsigned int p2 = pack2bf(a1.x, a1.y);
        unsigned int p3 = pack2bf(a1.z, a1.w);
        uint4 pv = make_uint4(p0, p1, p2, p3);
        bf16x8 af = __builtin_bit_cast(bf16x8, pv);
        bf16x8 bfv = *(const bf16x8*)(brow + (((ch * 2 + half) ^ kx) << 4));
        acc = __builtin_amdgcn_mfma_f32_32x32x16_bf16(af, bfv, acc, 0, 0, 0);
    }

    // epilogue: C (col=k, row=token) -> LDS transpose -> coalesced k-major
#pragma unroll
    for (int r = 0; r < 16; ++r) {
        int row = (r & 3) + 8 * (r >> 2) + 4 * half;   // token row within 32
        lt[l31][wv * 32 + row] = acc[r];
    }
    __syncthreads();
    float* o = lp + ((size_t)(dq * B + b) * KK) * S + st * 128;
#pragma unroll
    for (int i = 0; i < 4; ++i) {
        int slot = tid + i * 256;
        int k = slot >> 5, s4 = slot & 31;
        float4 v;
        v.x = lt[k][s4 * 4 + 0];
        v.y = lt[k][s4 * 4 + 1];
        v.z = lt[k][s4 * 4 + 2];
        v.w = lt[k][s4 * 4 + 3];
        *(float4*)(o + (size_t)k * S + s4 * 4) = v;
    }
}

// ---------------------------------------------------------------------------
// K2a: per (b,k, s-chunk 512): partial max + sum of exp. grid 2048. (unchanged)
// ---------------------------------------------------------------------------
__global__ __launch_bounds__(256) void k2a_partial(const float* __restrict__ lp,
                                                   float* __restrict__ pmax,
                                                   float* __restrict__ psum) {
    const int bid = blockIdx.x;
    const int c  = bid & 7;
    const int bk = bid >> 3;
    const int tid = threadIdx.x;
    const int wave = tid >> 6, lane = tid & 63;
    const size_t base = (size_t)bk * S + c * 512;

    float v0 = lp[base + tid]       + lp[1048576 + base + tid];
    float v1 = lp[base + tid + 256] + lp[1048576 + base + tid + 256];

    float m = fmaxf(v0, v1);
#pragma unroll
    for (int off = 32; off >= 1; off >>= 1) m = fmaxf(m, __shfl_xor(m, off, 64));
    __shared__ float sm_[4], sl[4];
    if (lane == 0) sm_[wave] = m;
    __syncthreads();
    const float M = fmaxf(fmaxf(sm_[0], sm_[1]), fmaxf(sm_[2], sm_[3]));

    float l = __expf(v0 - M) + __expf(v1 - M);
#pragma unroll
    for (int off = 32; off >= 1; off >>= 1) l += __shfl_xor(l, off, 64);
    if (lane == 0) sl[wave] = l;
    __syncthreads();
    if (tid == 0) {
        pmax[bid] = M;
        psum[bid] = sl[0] + sl[1] + sl[2] + sl[3];
    }
}

// ---------------------------------------------------------------------------
// K2c: combine partials, normalize; write wbT bf16 [b][k][s] AND pw fp32
// [b][s][k] via LDS transpose. grid = B*32. (unchanged)
// ---------------------------------------------------------------------------
__global__ __launch_bounds__(256) void k2c_norm(const float* __restrict__ lp,
                                                const float* __restrict__ pmax,
                                                const float* __restrict__ psum,
                                                unsigned short* __restrict__ wbT,
                                                float* __restrict__ pw_out) {
    __shared__ float tile[128][33];
    __shared__ float sM[32], sLinv[32];
    const int b  = blockIdx.x >> 5;
    const int sc = blockIdx.x & 31;
    const int s0 = sc * 128;
    const int tid = threadIdx.x;

    if (tid < 32) {
        const int k = tid;
        float M = -1e30f, L = 0.f;
#pragma unroll
        for (int c = 0; c < 8; ++c) {
            float mc = pmax[(b * KK + k) * 8 + c];
            float lc = psum[(b * KK + k) * 8 + c];
            float nM = fmaxf(M, mc);
            L = L * __expf(M - nM) + lc * __expf(mc - nM);
            M = nM;
        }
        sM[k] = M;
        sLinv[k] = 1.0f / L;
    }
    __syncthreads();

    const int sL = tid & 127;
    const int kh = tid >> 7;
#pragma unroll
    for (int kk = 0; kk < 16; ++kk) {
        const int k = kk * 2 + kh;
        const size_t idx = ((size_t)b * KK + k) * S + s0 + sL;
        float v = lp[idx] + lp[1048576 + idx];
        float w = __expf(v - sM[k]) * sLinv[k];
        wbT[idx] = f2bf(w);
        tile[sL][k] = w;
    }
    __syncthreads();

    float* ob = pw_out + ((size_t)b * S + s0) * KK;
#pragma unroll
    for (int i = 0; i < 4; ++i) {
        const int idx4 = tid + i * 256;
        const int sl = idx4 >> 3, kq = idx4 & 7;
        float4 v4 = make_float4(tile[sl][kq * 4 + 0], tile[sl][kq * 4 + 1],
                                tile[sl][kq * 4 + 2], tile[sl][kq * 4 + 3]);
        ((float4*)ob)[idx4] = v4;
    }
}

// ---------------------------------------------------------------------------
// K3: soft_slots via MFMA 32x32x16 bf16: C[k][d] = sum_s w[k][s] x[s][d].
// grid = 8b x 8 dg(128 d) x 8 sc(512 s) = 512, 4 waves.
// NEW: x tile [64 s][128 d] staged as *fp32* via global_load_lds dwordx4
// (no VGPR round-trip, no store-side cvt); B-frags built from bank-clean
// ds_read_b32 (+cvt on read, same total cvt count). w tile [32 k][64 s] bf16
// staged via global_load_lds with source-side XOR pre-swizzle; A-frags are
// swizzled ds_read_b128. One barrier per chunk: issue-stage(next) ->
// compute(cur) -> __syncthreads (vmcnt drain overlapped with compute).
// ---------------------------------------------------------------------------
__global__ __launch_bounds__(256) void k3_slots(const float* __restrict__ x,
                                                const unsigned short* __restrict__ wbT,
                                                float* __restrict__ part) {
    // LDS: x dbuf 2x32 KB @0, w dbuf 2x4 KB @65536  (72 KB -> 2 blocks/CU)
    __shared__ __align__(16) char sm[2 * 32768 + 2 * 4096];

    const int bid = blockIdx.x;
    const int sc = bid & 7;
    const int dg = (bid >> 3) & 7;
    const int b  = bid >> 6;
    const int tid = threadIdx.x;
    const int wv = __builtin_amdgcn_readfirstlane(tid >> 6);
    const int lane = tid & 63;
    const int l31 = lane & 31;
    const int half = lane >> 5;

    // x stage: instr t (0..7) covers rows {wv*16+2t, +1}; lane: row += half,
    // col16 = l31 (16 B each). Per chunk advance = 64 rows = 256 KB.
    const char* xsrc = (const char*)(x + ((size_t)(b * S + sc * 512 + wv * 16 + half)) * DD
                                       + dg * 128 + l31 * 4);
    // w stage: lane -> k = wv*8 + (lane>>3), blk_dst = lane&7,
    // src blk = blk_dst ^ (k&7)  (so LDS[k][blk] = global[k][blk^(k&7)]).
    const int wk = wv * 8 + (lane >> 3);
    const char* wsrc = (const char*)wbT + ((size_t)(b * KK + wk) * S + sc * 512) * 2
                                        + (((lane & 7) ^ (wk & 7)) << 4);

    char* const xb0 = sm;
    char* const wb0 = sm + 65536;

    auto stage = [&](int ch, int buf) {
        char* xb = xb0 + buf * 32768 + wv * (16 * 512);
        const char* xs = xsrc + (size_t)ch * (64 * DD * 4);
#pragma unroll
        for (int t = 0; t < 8; ++t)
            gload_lds16(xs + (size_t)t * (2 * DD * 4), xb + t * 1024);
        gload_lds16(wsrc + (size_t)ch * 128, wb0 + buf * 4096 + wv * 1024);
    };

    f32x16 acc;
#pragma unroll
    for (int r = 0; r < 16; ++r) acc[r] = 0.f;

    stage(0, 0);
    __syncthreads();   // compiler drains vmcnt(0) here

    const int col = wv * 32 + l31;   // d-col within 128-d tile
    const int kx = l31 & 7;

    for (int ch = 0; ch < 8; ++ch) {
        const int cur = ch & 1;
        if (ch < 7) stage(ch + 1, cur ^ 1);   // issue early, drain at barrier
        const float* xr = (const float*)(xb0 + cur * 32768);
        const char* wr = wb0 + cur * 4096 + (size_t)l31 * 128;
#pragma unroll
        for (int step = 0; step < 4; ++step) {
            // A-frag: w[k = l31][s = step*16 + half*8 + j]  (b128, swizzled)
            bf16x8 af = *(const bf16x8*)(wr + (((step * 2 + half) ^ kx) << 4));
            // B-frag: x[s = step*16 + half*8 + j][d = col]  (8 x b32 + cvt)
            const int sb = step * 16 + half * 8;
            unsigned int p0 = pack2bf(xr[(sb + 0) * 128 + col], xr[(sb + 1) * 128 + col]);
            unsigned int p1 = pack2bf(xr[(sb + 2) * 128 + col], xr[(sb + 3) * 128 + col]);
            unsigned int p2 = pack2bf(xr[(sb + 4) * 128 + col], xr[(sb + 5) * 128 + col]);
            unsigned int p3 = pack2bf(xr[(sb + 6) * 128 + col], xr[(sb + 7) * 128 + col]);
            uint4 pv = make_uint4(p0, p1, p2, p3);
            bf16x8 bfv = __builtin_bit_cast(bf16x8, pv);
            acc = __builtin_amdgcn_mfma_f32_32x32x16_bf16(af, bfv, acc, 0, 0, 0);
        }
        __syncthreads();
    }

    float* pp = part + (((size_t)sc * B + b) * KK) * DD + dg * 128 + col;
#pragma unroll
    for (int r = 0; r < 16; ++r) {
        int k = (r & 3) + 8 * (r >> 2) + 4 * half;
        pp[(size_t)k * DD] = acc[r];
    }
}

// ---------------------------------------------------------------------------
// K4: reduce 8 partials -> soft_slots + expert_inputs; fill expert_weights
// and expert_indices. grid 256. (unchanged)
// ---------------------------------------------------------------------------
__global__ __launch_bounds__(256) void k4_finalize(const float* __restrict__ part,
                                                   float* __restrict__ out) {
    const int idx = blockIdx.x * 256 + threadIdx.x;
    const float4* p4 = (const float4*)part;

    float4 sv = p4[idx];
#pragma unroll
    for (int c = 1; c < 8; ++c) {
        float4 t = p4[(size_t)c * 65536 + idx];
        sv.x += t.x; sv.y += t.y; sv.z += t.z; sv.w += t.w;
    }

    ((float4*)(out + 1572864))[idx] = sv;
    ((float4*)(out + 1835008))[idx] = sv;
    ((float4*)out)[idx] = make_float4(0.125f, 0.125f, 0.125f, 0.125f);
    float base = (float)((idx * 4) & 7);
    ((float4*)(out + 262144))[idx] = make_float4(base, base + 1.f, base + 2.f, base + 3.f);
}

extern "C" void kernel_launch(void* const* d_in, const int* in_sizes, int n_in,
                              void* d_out, int out_size, void* d_ws, size_t ws_size,
                              hipStream_t stream) {
    const float* x    = (const float*)d_in[0];
    const float* phi  = (const float*)d_in[1];
    const float* bias = (const float*)d_in[2];
    float* out = (float*)d_out;

    // ws layout (float units):
    //   lp    @ 0        (2 x 1048576: two d-partials, [dq][b][k][s])
    //   pmax  @ 2097152  (2048)
    //   psum  @ 2099200  (2048)
    //   wbT   @ 2101248  (1048576 u16 = 524288 f)
    //   phiT  @ 2625536  (32768 u16 = 16384 f)
    //   part  @ 2641920  (8 x 262144)
    float* ws = (float*)d_ws;
    float* lp   = ws;
    float* pmax = ws + 2097152;
    float* psum = ws + 2099200;
    unsigned short* wbT  = (unsigned short*)(ws + 2101248);
    unsigned short* phiT = (unsigned short*)(ws + 2625536);
    float* part = ws + 2641920;
    float* pw_out = out + 524288;

    k0_phit<<<dim3(32), dim3(256), 0, stream>>>(phi, phiT);
    k1_logits<<<dim3(512), dim3(256), 0, stream>>>(x, phiT, bias, lp);
    k2a_partial<<<dim3(2048), dim3(256), 0, stream>>>(lp, pmax, psum);
    k2c_norm<<<dim3(256), dim3(256), 0, stream>>>(lp, pmax, psum, wbT, pw_out);
    k3_slots<<<dim3(512), dim3(256), 0, stream>>>(x, wbT, part);
    k4_finalize<<<dim3(256), dim3(256), 0, stream>>>(part, out);
}

// Round 2
// 235.548 us; speedup vs baseline: 1.0066x; 1.0066x over previous
//
#include <hip/hip_runtime.h>
#include <hip/hip_bf16.h>

// SoftMoEGating: B=8, S=4096, D=1024, E=8, P=4, K=E*P=32
#define B 8
#define S 4096
#define DD 1024
#define KK 32

typedef __attribute__((ext_vector_type(8))) short bf16x8;
typedef __attribute__((ext_vector_type(16))) float f32x16;

static __device__ __forceinline__ unsigned short f2bf(float f) {
    unsigned int u = __builtin_bit_cast(unsigned int, f);
    u += 0x7FFFu + ((u >> 16) & 1u);     // RNE
    return (unsigned short)(u >> 16);
}

static __device__ __forceinline__ unsigned int pack2bf(float lo, float hi) {
    return (unsigned int)f2bf(lo) | ((unsigned int)f2bf(hi) << 16);
}

static __device__ __forceinline__ void gload_lds16(const void* g, void* l) {
    __builtin_amdgcn_global_load_lds(
        (const __attribute__((address_space(1))) unsigned int*)g,
        (__attribute__((address_space(3))) unsigned int*)l, 16, 0, 0);
}

// ---------------------------------------------------------------------------
// K0: phi [1024 d][32 k] fp32  ->  phiT [32 k][1024 d] bf16 (B-operand layout).
// ---------------------------------------------------------------------------
__global__ __launch_bounds__(256) void k0_phit(const float* __restrict__ phi,
                                               unsigned short* __restrict__ phiT) {
    __shared__ float lt[32][33];
    const int d0 = blockIdx.x * 32;
    const int tid = threadIdx.x;
#pragma unroll
    for (int i = 0; i < 4; ++i) {
        int slot = tid + i * 256;
        int d = slot >> 5, k = slot & 31;
        lt[d][k] = phi[(size_t)(d0 + d) * KK + k];
    }
    __syncthreads();
    const int k = tid >> 3, c = tid & 7, d = c * 4;
    short4 pk;
    pk.x = (short)f2bf(lt[d + 0][k]);
    pk.y = (short)f2bf(lt[d + 1][k]);
    pk.z = (short)f2bf(lt[d + 2][k]);
    pk.w = (short)f2bf(lt[d + 3][k]);
    *(short4*)(phiT + (size_t)k * DD + d0 + d) = pk;
}

// ---------------------------------------------------------------------------
// K1: logits, full-D per block. grid = 8b x 32 stile(128 s) = 256, 4 waves.
// Wave w owns tokens [w*32, w*32+32) x all 32 k; K-loop = 1024 d (64 MFMA).
// phiT fully LDS-resident (64 KB, 16B-block XOR-swizzled). A-frags loaded
// directly from global (zero intra-block x reuse -> no staging).
// Epilogue: C -> LDS transpose (overlaying phiT, now dead) -> coalesced
// k-major lp store + FUSED per-chunk softmax partials (max, sum-exp) so the
// former K2a kernel disappears. Single lp buffer (bias folded into acc).
// ---------------------------------------------------------------------------
__global__ __launch_bounds__(256) void k1_logits(const float* __restrict__ x,
                                                 const unsigned short* __restrict__ phiT,
                                                 const float* __restrict__ bias,
                                                 float* __restrict__ lp,
                                                 float* __restrict__ pmax,
                                                 float* __restrict__ psum) {
    __shared__ __align__(16) char sm[65536];   // phiT tile; lt overlays later

    const int bid = blockIdx.x;
    const int st = bid & 31;
    const int b  = bid >> 5;
    const int tid = threadIdx.x;
    const int wv = __builtin_amdgcn_readfirstlane(tid >> 6);
    const int lane = tid & 63;
    const int l31 = lane & 31;
    const int half = lane >> 5;

    // stage phiT [32 k][1024 d] bf16 = 64 KB, 16B-block XOR swizzle (per k)
    {
        const uint4* pg = (const uint4*)phiT;   // 128 uint4 per k-row
#pragma unroll
        for (int i = 0; i < 16; ++i) {
            int slot = tid + i * 256;
            int k = slot >> 7, blk = slot & 127;
            uint4 v = pg[(size_t)k * 128 + blk];
            *(uint4*)(sm + (size_t)k * 2048 + ((blk ^ (k & 7)) << 4)) = v;
        }
    }

    f32x16 acc;
    {
        float bv = bias[l31];
#pragma unroll
        for (int r = 0; r < 16; ++r) acc[r] = bv;
    }
    __syncthreads();

    // A: token row = st*128 + wv*32 + l31; d-cols = ch*16 + half*8 + j
    const float* xg = x + ((size_t)(b * S + st * 128 + wv * 32 + l31)) * DD + half * 8;
    const int kx = l31 & 7;
    const char* brow = sm + (size_t)l31 * 2048;

#pragma unroll 8
    for (int ch = 0; ch < 64; ++ch) {
        float4 a0 = *(const float4*)(xg + ch * 16);
        float4 a1 = *(const float4*)(xg + ch * 16 + 4);
        unsigned int p0 = pack2bf(a0.x, a0.y);
        unsigned int p1 = pack2bf(a0.z, a0.w);
        unsigned int p2 = pack2bf(a1.x, a1.y);
        unsigned int p3 = pack2bf(a1.z, a1.w);
        uint4 pv = make_uint4(p0, p1, p2, p3);
        bf16x8 af = __builtin_bit_cast(bf16x8, pv);
        bf16x8 bfv = *(const bf16x8*)(brow + (((ch * 2 + half) ^ kx) << 4));
        acc = __builtin_amdgcn_mfma_f32_32x32x16_bf16(af, bfv, acc, 0, 0, 0);
    }

    __syncthreads();                       // all MFMAs done; phiT tile is dead
    float* lt = (float*)sm;                // [32 k][129 s] fp32 (16.5 KB)
#pragma unroll
    for (int r = 0; r < 16; ++r) {
        int row = (r & 3) + 8 * (r >> 2) + 4 * half;   // token row within 32
        lt[(size_t)l31 * 129 + wv * 32 + row] = acc[r];
    }
    __syncthreads();

    // coalesced k-major lp store
    float* o = lp + ((size_t)b * KK) * S + st * 128;
#pragma unroll
    for (int i = 0; i < 4; ++i) {
        int slot = tid + i * 256;
        int k = slot >> 5, s4 = slot & 31;
        float4 v;
        v.x = lt[k * 129 + s4 * 4 + 0];
        v.y = lt[k * 129 + s4 * 4 + 1];
        v.z = lt[k * 129 + s4 * 4 + 2];
        v.w = lt[k * 129 + s4 * 4 + 3];
        *(float4*)(o + (size_t)k * S + s4 * 4) = v;
    }

    // fused softmax partials: k = tid>>3, 8 lanes x 16 tokens each
    const int pk = tid >> 3, pj = tid & 7;
    const float* lr = lt + (size_t)pk * 129 + pj * 16;
    float m = lr[0];
#pragma unroll
    for (int i = 1; i < 16; ++i) m = fmaxf(m, lr[i]);
#pragma unroll
    for (int off = 4; off >= 1; off >>= 1) m = fmaxf(m, __shfl_xor(m, off, 64));
    float l = 0.f;
#pragma unroll
    for (int i = 0; i < 16; ++i) l += __expf(lr[i] - m);
#pragma unroll
    for (int off = 4; off >= 1; off >>= 1) l += __shfl_xor(l, off, 64);
    if (pj == 0) {
        pmax[((size_t)b * KK + pk) * 32 + st] = m;
        psum[((size_t)b * KK + pk) * 32 + st] = l;
    }
}

// ---------------------------------------------------------------------------
// K2c: combine 32 partials, normalize; write wbT bf16 [b][k][s] AND pw fp32
// [b][s][k] via LDS transpose. grid = B*32 (s-chunks of 128).
// ---------------------------------------------------------------------------
__global__ __launch_bounds__(256) void k2c_norm(const float* __restrict__ lp,
                                                const float* __restrict__ pmax,
                                                const float* __restrict__ psum,
                                                unsigned short* __restrict__ wbT,
                                                float* __restrict__ pw_out) {
    __shared__ float tile[128][33];
    __shared__ float sM[32], sLinv[32];
    const int b  = blockIdx.x >> 5;
    const int sc = blockIdx.x & 31;
    const int s0 = sc * 128;
    const int tid = threadIdx.x;

    if (tid < 32) {
        const int k = tid;
        float M = -1e30f, L = 0.f;
#pragma unroll
        for (int c = 0; c < 32; ++c) {
            float mc = pmax[((size_t)b * KK + k) * 32 + c];
            float lc = psum[((size_t)b * KK + k) * 32 + c];
            float nM = fmaxf(M, mc);
            L = L * __expf(M - nM) + lc * __expf(mc - nM);
            M = nM;
        }
        sM[k] = M;
        sLinv[k] = 1.0f / L;
    }
    __syncthreads();

    const int sL = tid & 127;
    const int kh = tid >> 7;
#pragma unroll
    for (int kk = 0; kk < 16; ++kk) {
        const int k = kk * 2 + kh;
        const size_t idx = ((size_t)b * KK + k) * S + s0 + sL;
        float v = lp[idx];
        float w = __expf(v - sM[k]) * sLinv[k];
        wbT[idx] = f2bf(w);
        tile[sL][k] = w;
    }
    __syncthreads();

    float* ob = pw_out + ((size_t)b * S + s0) * KK;
#pragma unroll
    for (int i = 0; i < 4; ++i) {
        const int idx4 = tid + i * 256;
        const int sl = idx4 >> 3, kq = idx4 & 7;
        float4 v4 = make_float4(tile[sl][kq * 4 + 0], tile[sl][kq * 4 + 1],
                                tile[sl][kq * 4 + 2], tile[sl][kq * 4 + 3]);
        ((float4*)ob)[idx4] = v4;
    }
}

// ---------------------------------------------------------------------------
// K3: soft_slots via MFMA 32x32x16 bf16: C[k][d] = sum_s w[k][s] x[s][d].
// grid = 8b x 8 dg(128 d) x 8 sc(512 s) = 512, 4 waves. (unchanged)
// ---------------------------------------------------------------------------
__global__ __launch_bounds__(256) void k3_slots(const float* __restrict__ x,
                                                const unsigned short* __restrict__ wbT,
                                                float* __restrict__ part) {
    // LDS: x dbuf 2x32 KB @0, w dbuf 2x4 KB @65536  (72 KB -> 2 blocks/CU)
    __shared__ __align__(16) char sm[2 * 32768 + 2 * 4096];

    const int bid = blockIdx.x;
    const int sc = bid & 7;
    const int dg = (bid >> 3) & 7;
    const int b  = bid >> 6;
    const int tid = threadIdx.x;
    const int wv = __builtin_amdgcn_readfirstlane(tid >> 6);
    const int lane = tid & 63;
    const int l31 = lane & 31;
    const int half = lane >> 5;

    const char* xsrc = (const char*)(x + ((size_t)(b * S + sc * 512 + wv * 16 + half)) * DD
                                       + dg * 128 + l31 * 4);
    const int wk = wv * 8 + (lane >> 3);
    const char* wsrc = (const char*)wbT + ((size_t)(b * KK + wk) * S + sc * 512) * 2
                                        + (((lane & 7) ^ (wk & 7)) << 4);

    char* const xb0 = sm;
    char* const wb0 = sm + 65536;

    auto stage = [&](int ch, int buf) {
        char* xb = xb0 + buf * 32768 + wv * (16 * 512);
        const char* xs = xsrc + (size_t)ch * (64 * DD * 4);
#pragma unroll
        for (int t = 0; t < 8; ++t)
            gload_lds16(xs + (size_t)t * (2 * DD * 4), xb + t * 1024);
        gload_lds16(wsrc + (size_t)ch * 128, wb0 + buf * 4096 + wv * 1024);
    };

    f32x16 acc;
#pragma unroll
    for (int r = 0; r < 16; ++r) acc[r] = 0.f;

    stage(0, 0);
    __syncthreads();

    const int col = wv * 32 + l31;   // d-col within 128-d tile
    const int kx = l31 & 7;

    for (int ch = 0; ch < 8; ++ch) {
        const int cur = ch & 1;
        if (ch < 7) stage(ch + 1, cur ^ 1);
        const float* xr = (const float*)(xb0 + cur * 32768);
        const char* wr = wb0 + cur * 4096 + (size_t)l31 * 128;
#pragma unroll
        for (int step = 0; step < 4; ++step) {
            bf16x8 af = *(const bf16x8*)(wr + (((step * 2 + half) ^ kx) << 4));
            const int sb = step * 16 + half * 8;
            unsigned int p0 = pack2bf(xr[(sb + 0) * 128 + col], xr[(sb + 1) * 128 + col]);
            unsigned int p1 = pack2bf(xr[(sb + 2) * 128 + col], xr[(sb + 3) * 128 + col]);
            unsigned int p2 = pack2bf(xr[(sb + 4) * 128 + col], xr[(sb + 5) * 128 + col]);
            unsigned int p3 = pack2bf(xr[(sb + 6) * 128 + col], xr[(sb + 7) * 128 + col]);
            uint4 pv = make_uint4(p0, p1, p2, p3);
            bf16x8 bfv = __builtin_bit_cast(bf16x8, pv);
            acc = __builtin_amdgcn_mfma_f32_32x32x16_bf16(af, bfv, acc, 0, 0, 0);
        }
        __syncthreads();
    }

    float* pp = part + (((size_t)sc * B + b) * KK) * DD + dg * 128 + col;
#pragma unroll
    for (int r = 0; r < 16; ++r) {
        int k = (r & 3) + 8 * (r >> 2) + 4 * half;
        pp[(size_t)k * DD] = acc[r];
    }
}

// ---------------------------------------------------------------------------
// K4: reduce 8 partials -> soft_slots + expert_inputs; fill expert_weights
// and expert_indices. grid 256. (unchanged)
// ---------------------------------------------------------------------------
__global__ __launch_bounds__(256) void k4_finalize(const float* __restrict__ part,
                                                   float* __restrict__ out) {
    const int idx = blockIdx.x * 256 + threadIdx.x;
    const float4* p4 = (const float4*)part;

    float4 sv = p4[idx];
#pragma unroll
    for (int c = 1; c < 8; ++c) {
        float4 t = p4[(size_t)c * 65536 + idx];
        sv.x += t.x; sv.y += t.y; sv.z += t.z; sv.w += t.w;
    }

    ((float4*)(out + 1572864))[idx] = sv;
    ((float4*)(out + 1835008))[idx] = sv;
    ((float4*)out)[idx] = make_float4(0.125f, 0.125f, 0.125f, 0.125f);
    float base = (float)((idx * 4) & 7);
    ((float4*)(out + 262144))[idx] = make_float4(base, base + 1.f, base + 2.f, base + 3.f);
}

extern "C" void kernel_launch(void* const* d_in, const int* in_sizes, int n_in,
                              void* d_out, int out_size, void* d_ws, size_t ws_size,
                              hipStream_t stream) {
    const float* x    = (const float*)d_in[0];
    const float* phi  = (const float*)d_in[1];
    const float* bias = (const float*)d_in[2];
    float* out = (float*)d_out;

    // ws layout (float units):
    //   lp    @ 0        (1048576: [b][k][s], bias included)
    //   pmax  @ 1048576  (8192: [b][k][32 chunks])
    //   psum  @ 1056768  (8192)
    //   wbT   @ 1064960  (1048576 u16 = 524288 f)
    //   phiT  @ 1589248  (32768 u16 = 16384 f)
    //   part  @ 1605632  (8 x 262144)
    float* ws = (float*)d_ws;
    float* lp   = ws;
    float* pmax = ws + 1048576;
    float* psum = ws + 1056768;
    unsigned short* wbT  = (unsigned short*)(ws + 1064960);
    unsigned short* phiT = (unsigned short*)(ws + 1589248);
    float* part = ws + 1605632;
    float* pw_out = out + 524288;

    k0_phit<<<dim3(32), dim3(256), 0, stream>>>(phi, phiT);
    k1_logits<<<dim3(256), dim3(256), 0, stream>>>(x, phiT, bias, lp, pmax, psum);
    k2c_norm<<<dim3(256), dim3(256), 0, stream>>>(lp, pmax, psum, wbT, pw_out);
    k3_slots<<<dim3(512), dim3(256), 0, stream>>>(x, wbT, part);
    k4_finalize<<<dim3(256), dim3(256), 0, stream>>>(part, out);
}

// Round 3
// 228.082 us; speedup vs baseline: 1.0396x; 1.0327x over previous
//
#include <hip/hip_runtime.h>
#include <hip/hip_bf16.h>

// SoftMoEGating: B=8, S=4096, D=1024, E=8, P=4, K=E*P=32
#define B 8
#define S 4096
#define DD 1024
#define KK 32

typedef __attribute__((ext_vector_type(8))) short bf16x8;
typedef __attribute__((ext_vector_type(16))) float f32x16;

static __device__ __forceinline__ unsigned short f2bf(float f) {
    unsigned int u = __builtin_bit_cast(unsigned int, f);
    u += 0x7FFFu + ((u >> 16) & 1u);     // RNE
    return (unsigned short)(u >> 16);
}

static __device__ __forceinline__ unsigned int pack2bf(float lo, float hi) {
    return (unsigned int)f2bf(lo) | ((unsigned int)f2bf(hi) << 16);
}

static __device__ __forceinline__ void gload_lds16(const void* g, void* l) {
    __builtin_amdgcn_global_load_lds(
        (const __attribute__((address_space(1))) unsigned int*)g,
        (__attribute__((address_space(3))) unsigned int*)l, 16, 0, 0);
}

// ---------------------------------------------------------------------------
// K0: phi [1024 d][32 k] fp32  ->  phiT [32 k][1024 d] bf16 (B-operand layout).
// ---------------------------------------------------------------------------
__global__ __launch_bounds__(256) void k0_phit(const float* __restrict__ phi,
                                               unsigned short* __restrict__ phiT) {
    __shared__ float lt[32][33];
    const int d0 = blockIdx.x * 32;
    const int tid = threadIdx.x;
#pragma unroll
    for (int i = 0; i < 4; ++i) {
        int slot = tid + i * 256;
        int d = slot >> 5, k = slot & 31;
        lt[d][k] = phi[(size_t)(d0 + d) * KK + k];
    }
    __syncthreads();
    const int k = tid >> 3, c = tid & 7, d = c * 4;
    short4 pk;
    pk.x = (short)f2bf(lt[d + 0][k]);
    pk.y = (short)f2bf(lt[d + 1][k]);
    pk.z = (short)f2bf(lt[d + 2][k]);
    pk.w = (short)f2bf(lt[d + 3][k]);
    *(short4*)(phiT + (size_t)k * DD + d0 + d) = pk;
}

// ---------------------------------------------------------------------------
// K1: logits. grid = 8b x 64 stile(64 s) = 512 blocks -> 2 blocks/CU
// (was 256 = 1 block/CU = 1 wave/SIMD: latency-exposed). 4 waves: wave
// (wv>>1 = row-group of 32 tokens, wv&1 = d-half of 512). phiT fully
// LDS-resident (64 KB, swizzled). A-frags straight from global. Epilogue:
// d-half partial sums combined through LDS (phiT dead), coalesced k-major
// lp store + fused per-64-token softmax partials (max, sum-exp).
// ---------------------------------------------------------------------------
__global__ __launch_bounds__(256) void k1_logits(const float* __restrict__ x,
                                                 const unsigned short* __restrict__ phiT,
                                                 const float* __restrict__ bias,
                                                 float* __restrict__ lp,
                                                 float* __restrict__ pmax,
                                                 float* __restrict__ psum) {
    __shared__ __align__(16) char sm[65536];   // phiT tile; lt overlays later

    const int bid = blockIdx.x;
    const int st = bid & 63;
    const int b  = bid >> 6;
    const int tid = threadIdx.x;
    const int wv = __builtin_amdgcn_readfirstlane(tid >> 6);
    const int lane = tid & 63;
    const int l31 = lane & 31;
    const int half = lane >> 5;
    const int r0 = (wv >> 1) * 32;   // token row group within 64
    const int h  = wv & 1;           // d-half

    // stage phiT [32 k][1024 d] bf16 = 64 KB, 16B-block XOR swizzle (per k)
    {
        const uint4* pg = (const uint4*)phiT;   // 128 uint4 per k-row
#pragma unroll
        for (int i = 0; i < 16; ++i) {
            int slot = tid + i * 256;
            int k = slot >> 7, blk = slot & 127;
            uint4 v = pg[(size_t)k * 128 + blk];
            *(uint4*)(sm + (size_t)k * 2048 + ((blk ^ (k & 7)) << 4)) = v;
        }
    }

    f32x16 acc;
    {
        float bv = (h == 0) ? bias[l31] : 0.f;   // bias once per (token,k)
#pragma unroll
        for (int r = 0; r < 16; ++r) acc[r] = bv;
    }
    __syncthreads();

    // A: token row = st*64 + r0 + l31; d-cols = h*512 + ch*16 + half*8 + j
    const float* xg = x + ((size_t)(b * S + st * 64 + r0 + l31)) * DD
                        + h * 512 + half * 8;
    const int kx = l31 & 7;
    const char* brow = sm + (size_t)l31 * 2048;

#pragma unroll 8
    for (int ch = 0; ch < 32; ++ch) {
        float4 a0 = *(const float4*)(xg + ch * 16);
        float4 a1 = *(const float4*)(xg + ch * 16 + 4);
        unsigned int p0 = pack2bf(a0.x, a0.y);
        unsigned int p1 = pack2bf(a0.z, a0.w);
        unsigned int p2 = pack2bf(a1.x, a1.y);
        unsigned int p3 = pack2bf(a1.z, a1.w);
        uint4 pv = make_uint4(p0, p1, p2, p3);
        bf16x8 af = __builtin_bit_cast(bf16x8, pv);
        int blk = h * 64 + ch * 2 + half;
        bf16x8 bfv = *(const bf16x8*)(brow + ((blk ^ kx) << 4));
        acc = __builtin_amdgcn_mfma_f32_32x32x16_bf16(af, bfv, acc, 0, 0, 0);
    }

    __syncthreads();                       // all MFMAs done; phiT tile is dead
    float* lt = (float*)sm;                // [32 k][65 s] fp32 (8.3 KB)
    if (h == 0) {
#pragma unroll
        for (int r = 0; r < 16; ++r) {
            int row = (r & 3) + 8 * (r >> 2) + 4 * half;   // token row in 32
            lt[(size_t)l31 * 65 + r0 + row] = acc[r];
        }
    }
    __syncthreads();
    if (h == 1) {
#pragma unroll
        for (int r = 0; r < 16; ++r) {
            int row = (r & 3) + 8 * (r >> 2) + 4 * half;
            lt[(size_t)l31 * 65 + r0 + row] += acc[r];
        }
    }
    __syncthreads();

    // coalesced k-major lp store (32 k x 64 s = 512 float4)
    float* o = lp + ((size_t)b * KK) * S + st * 64;
#pragma unroll
    for (int i = 0; i < 2; ++i) {
        int slot = tid + i * 256;
        int k = slot >> 4, s4 = slot & 15;
        float4 v;
        v.x = lt[k * 65 + s4 * 4 + 0];
        v.y = lt[k * 65 + s4 * 4 + 1];
        v.z = lt[k * 65 + s4 * 4 + 2];
        v.w = lt[k * 65 + s4 * 4 + 3];
        *(float4*)(o + (size_t)k * S + s4 * 4) = v;
    }

    // fused softmax partials: k = tid>>3, 8 lanes x 8 tokens each
    const int pk = tid >> 3, pj = tid & 7;
    const float* lr = lt + (size_t)pk * 65 + pj * 8;
    float m = lr[0];
#pragma unroll
    for (int i = 1; i < 8; ++i) m = fmaxf(m, lr[i]);
#pragma unroll
    for (int off = 4; off >= 1; off >>= 1) m = fmaxf(m, __shfl_xor(m, off, 64));
    float l = 0.f;
#pragma unroll
    for (int i = 0; i < 8; ++i) l += __expf(lr[i] - m);
#pragma unroll
    for (int off = 4; off >= 1; off >>= 1) l += __shfl_xor(l, off, 64);
    if (pj == 0) {
        pmax[((size_t)b * KK + pk) * 64 + st] = m;
        psum[((size_t)b * KK + pk) * 64 + st] = l;
    }
}

// ---------------------------------------------------------------------------
// K2c: combine 64 partials (8 lanes/k, shfl-merged), normalize; write wbT
// bf16 [b][k][s] AND pw fp32 [b][s][k] via LDS transpose. grid = B*32.
// ---------------------------------------------------------------------------
__global__ __launch_bounds__(256) void k2c_norm(const float* __restrict__ lp,
                                                const float* __restrict__ pmax,
                                                const float* __restrict__ psum,
                                                unsigned short* __restrict__ wbT,
                                                float* __restrict__ pw_out) {
    __shared__ float tile[128][33];
    __shared__ float sM[32], sLinv[32];
    const int b  = blockIdx.x >> 5;
    const int sc = blockIdx.x & 31;
    const int s0 = sc * 128;
    const int tid = threadIdx.x;

    {   // 32 k x 8 lanes; each lane merges 8 chunks, then shfl tree-merge
        const int k = tid >> 3, pj = tid & 7;
        float M = -1e30f, L = 0.f;
#pragma unroll
        for (int c = 0; c < 8; ++c) {
            int cc = pj * 8 + c;
            float mc = pmax[((size_t)b * KK + k) * 64 + cc];
            float lc = psum[((size_t)b * KK + k) * 64 + cc];
            float nM = fmaxf(M, mc);
            L = L * __expf(M - nM) + lc * __expf(mc - nM);
            M = nM;
        }
#pragma unroll
        for (int off = 4; off >= 1; off >>= 1) {
            float Mo = __shfl_xor(M, off, 64);
            float Lo = __shfl_xor(L, off, 64);
            float nM = fmaxf(M, Mo);
            L = L * __expf(M - nM) + Lo * __expf(Mo - nM);
            M = nM;
        }
        if (pj == 0) {
            sM[k] = M;
            sLinv[k] = 1.0f / L;
        }
    }
    __syncthreads();

    const int sL = tid & 127;
    const int kh = tid >> 7;
#pragma unroll
    for (int kk = 0; kk < 16; ++kk) {
        const int k = kk * 2 + kh;
        const size_t idx = ((size_t)b * KK + k) * S + s0 + sL;
        float v = lp[idx];
        float w = __expf(v - sM[k]) * sLinv[k];
        wbT[idx] = f2bf(w);
        tile[sL][k] = w;
    }
    __syncthreads();

    float* ob = pw_out + ((size_t)b * S + s0) * KK;
#pragma unroll
    for (int i = 0; i < 4; ++i) {
        const int idx4 = tid + i * 256;
        const int sl = idx4 >> 3, kq = idx4 & 7;
        float4 v4 = make_float4(tile[sl][kq * 4 + 0], tile[sl][kq * 4 + 1],
                                tile[sl][kq * 4 + 2], tile[sl][kq * 4 + 3]);
        ((float4*)ob)[idx4] = v4;
    }
}

// ---------------------------------------------------------------------------
// K3: soft_slots via MFMA 32x32x16 bf16: C[k][d] = sum_s w[k][s] x[s][d].
// grid = 8b x 8 dg(128 d) x 8 sc(512 s) = 512, 4 waves. (unchanged)
// ---------------------------------------------------------------------------
__global__ __launch_bounds__(256) void k3_slots(const float* __restrict__ x,
                                                const unsigned short* __restrict__ wbT,
                                                float* __restrict__ part) {
    // LDS: x dbuf 2x32 KB @0, w dbuf 2x4 KB @65536  (72 KB -> 2 blocks/CU)
    __shared__ __align__(16) char sm[2 * 32768 + 2 * 4096];

    const int bid = blockIdx.x;
    const int sc = bid & 7;
    const int dg = (bid >> 3) & 7;
    const int b  = bid >> 6;
    const int tid = threadIdx.x;
    const int wv = __builtin_amdgcn_readfirstlane(tid >> 6);
    const int lane = tid & 63;
    const int l31 = lane & 31;
    const int half = lane >> 5;

    const char* xsrc = (const char*)(x + ((size_t)(b * S + sc * 512 + wv * 16 + half)) * DD
                                       + dg * 128 + l31 * 4);
    const int wk = wv * 8 + (lane >> 3);
    const char* wsrc = (const char*)wbT + ((size_t)(b * KK + wk) * S + sc * 512) * 2
                                        + (((lane & 7) ^ (wk & 7)) << 4);

    char* const xb0 = sm;
    char* const wb0 = sm + 65536;

    auto stage = [&](int ch, int buf) {
        char* xb = xb0 + buf * 32768 + wv * (16 * 512);
        const char* xs = xsrc + (size_t)ch * (64 * DD * 4);
#pragma unroll
        for (int t = 0; t < 8; ++t)
            gload_lds16(xs + (size_t)t * (2 * DD * 4), xb + t * 1024);
        gload_lds16(wsrc + (size_t)ch * 128, wb0 + buf * 4096 + wv * 1024);
    };

    f32x16 acc;
#pragma unroll
    for (int r = 0; r < 16; ++r) acc[r] = 0.f;

    stage(0, 0);
    __syncthreads();

    const int col = wv * 32 + l31;   // d-col within 128-d tile
    const int kx = l31 & 7;

    for (int ch = 0; ch < 8; ++ch) {
        const int cur = ch & 1;
        if (ch < 7) stage(ch + 1, cur ^ 1);
        const float* xr = (const float*)(xb0 + cur * 32768);
        const char* wr = wb0 + cur * 4096 + (size_t)l31 * 128;
#pragma unroll
        for (int step = 0; step < 4; ++step) {
            bf16x8 af = *(const bf16x8*)(wr + (((step * 2 + half) ^ kx) << 4));
            const int sb = step * 16 + half * 8;
            unsigned int p0 = pack2bf(xr[(sb + 0) * 128 + col], xr[(sb + 1) * 128 + col]);
            unsigned int p1 = pack2bf(xr[(sb + 2) * 128 + col], xr[(sb + 3) * 128 + col]);
            unsigned int p2 = pack2bf(xr[(sb + 4) * 128 + col], xr[(sb + 5) * 128 + col]);
            unsigned int p3 = pack2bf(xr[(sb + 6) * 128 + col], xr[(sb + 7) * 128 + col]);
            uint4 pv = make_uint4(p0, p1, p2, p3);
            bf16x8 bfv = __builtin_bit_cast(bf16x8, pv);
            acc = __builtin_amdgcn_mfma_f32_32x32x16_bf16(af, bfv, acc, 0, 0, 0);
        }
        __syncthreads();
    }

    float* pp = part + (((size_t)sc * B + b) * KK) * DD + dg * 128 + col;
#pragma unroll
    for (int r = 0; r < 16; ++r) {
        int k = (r & 3) + 8 * (r >> 2) + 4 * half;
        pp[(size_t)k * DD] = acc[r];
    }
}

// ---------------------------------------------------------------------------
// K4: reduce 8 partials -> soft_slots + expert_inputs; fill expert_weights
// and expert_indices. grid 256. (unchanged)
// ---------------------------------------------------------------------------
__global__ __launch_bounds__(256) void k4_finalize(const float* __restrict__ part,
                                                   float* __restrict__ out) {
    const int idx = blockIdx.x * 256 + threadIdx.x;
    const float4* p4 = (const float4*)part;

    float4 sv = p4[idx];
#pragma unroll
    for (int c = 1; c < 8; ++c) {
        float4 t = p4[(size_t)c * 65536 + idx];
        sv.x += t.x; sv.y += t.y; sv.z += t.z; sv.w += t.w;
    }

    ((float4*)(out + 1572864))[idx] = sv;
    ((float4*)(out + 1835008))[idx] = sv;
    ((float4*)out)[idx] = make_float4(0.125f, 0.125f, 0.125f, 0.125f);
    float base = (float)((idx * 4) & 7);
    ((float4*)(out + 262144))[idx] = make_float4(base, base + 1.f, base + 2.f, base + 3.f);
}

extern "C" void kernel_launch(void* const* d_in, const int* in_sizes, int n_in,
                              void* d_out, int out_size, void* d_ws, size_t ws_size,
                              hipStream_t stream) {
    const float* x    = (const float*)d_in[0];
    const float* phi  = (const float*)d_in[1];
    const float* bias = (const float*)d_in[2];
    float* out = (float*)d_out;

    // ws layout (float units):
    //   lp    @ 0        (1048576: [b][k][s], bias included)
    //   pmax  @ 1048576  (16384: [b][k][64 chunks])
    //   psum  @ 1064960  (16384)
    //   wbT   @ 1081344  (1048576 u16 = 524288 f)
    //   phiT  @ 1605632  (32768 u16 = 16384 f)
    //   part  @ 1622016  (8 x 262144)
    float* ws = (float*)d_ws;
    float* lp   = ws;
    float* pmax = ws + 1048576;
    float* psum = ws + 1064960;
    unsigned short* wbT  = (unsigned short*)(ws + 1081344);
    unsigned short* phiT = (unsigned short*)(ws + 1605632);
    float* part = ws + 1622016;
    float* pw_out = out + 524288;

    k0_phit<<<dim3(32), dim3(256), 0, stream>>>(phi, phiT);
    k1_logits<<<dim3(512), dim3(256), 0, stream>>>(x, phiT, bias, lp, pmax, psum);
    k2c_norm<<<dim3(256), dim3(256), 0, stream>>>(lp, pmax, psum, wbT, pw_out);
    k3_slots<<<dim3(512), dim3(256), 0, stream>>>(x, wbT, part);
    k4_finalize<<<dim3(256), dim3(256), 0, stream>>>(part, out);
}